// Round 1
// baseline (354.929 us; speedup 1.0000x reference)
//
#include <hip/hip_runtime.h>
#include <hip/hip_cooperative_groups.h>
#include <cmath>

namespace cg = cooperative_groups;

namespace {
constexpr int Hh = 224, Ww = 448;
constexpr int Tt = 2, Vv = 2, GH = 56, GW = 112;
constexpr int Nn = Vv * GH * GW;       // 12544 gaussians per (t) set
constexpr int TV = Tt * Vv;            // 4 render views
constexpr int TOT = TV * Nn;           // 50176 (view,gaussian) pairs
constexpr int HW = Hh * Ww;            // 100352
constexpr int TILE = 8;                // 8x8 tiles, one wave per tile
constexpr int NTX = Ww / TILE;         // 56
constexpr int NTY = Hh / TILE;         // 28
constexpr int NTILES = TV * NTX * NTY; // 6272
constexpr int CAP_T = 256;             // per-tile list capacity (expected peak ~80)

constexpr size_t RGB_SZ = (size_t)TV * 3 * HW;   // 1204224
constexpr size_t AL_SZ  = (size_t)TV * HW;       // 401408
constexpr size_t OFF_RGB_STA = 0;
constexpr size_t OFF_RGB_DYN = RGB_SZ;
constexpr size_t OFF_RGB_ALL = 2 * RGB_SZ;
constexpr size_t OFF_AL_STA  = 3 * RGB_SZ;
constexpr size_t OFF_AL_DYN  = 3 * RGB_SZ + AL_SZ;
constexpr size_t OFF_AL_ALL  = 3 * RGB_SZ + 2 * AL_SZ;
constexpr size_t OFF_SEM     = 3 * RGB_SZ + 3 * AL_SZ;
constexpr size_t OFF_SM      = OFF_SEM + RGB_SZ;
constexpr size_t OFF_TOUCH   = OFF_SM + 1;

// ---- ws layout (floats) ----
// Packed per-(tv,n) gaussian records, 3 float4 arrays:
//   QA = (z, u, v, sig) | QB = (pk_bits, r, g, b) | QC = (aAll, aDyn, aSta, 0)
// then: 4 f sum_sigma | 4 i cnt | 1 i touch-acc | 1 i ticket |
//       NTILES i tile-counters | NTILES*CAP_T i tile lists
constexpr size_t WS_QA   = 0;
constexpr size_t WS_QB   = (size_t)4 * TOT;
constexpr size_t WS_QC   = (size_t)8 * TOT;
constexpr size_t WS_SUM  = (size_t)12 * TOT;
constexpr size_t WS_CNT  = WS_SUM + 4;
constexpr size_t WS_TOUCH  = WS_CNT + 4;
constexpr size_t WS_TICKET = WS_TOUCH + 1;
constexpr size_t WS_TCNT = WS_TICKET + 1;
constexpr size_t WS_LIST = WS_TCNT + NTILES;
constexpr int    N_ZERO  = 10 + NTILES;  // Wsum+Wcnt+touch+ticket+Wtcnt
} // namespace

__device__ inline unsigned long long shfl_xor_u64(unsigned long long x, int m) {
  unsigned int lo = (unsigned int)x, hi = (unsigned int)(x >> 32);
  lo = __shfl_xor(lo, m, 64);
  hi = __shfl_xor(hi, m, 64);
  return ((unsigned long long)hi << 32) | lo;
}

// ---- phase A: zero counter region + copy sem -> out. grid = TOT threads. ----
__device__ __forceinline__ void phaseA_body(const float4* __restrict__ sem,
                                            float4* __restrict__ dst,
                                            float* __restrict__ ws, int idx) {
  int* Z = (int*)(ws + WS_SUM);
  if (idx < N_ZERO) Z[idx] = 0;   // N_ZERO = 6282 <= TOT
  // RGB_SZ/4 = 301056 = 6 * TOT exactly; coalesced grid-stride copy
  for (int i = idx; i < (int)(RGB_SZ / 4); i += TOT) dst[i] = sem[i];
}

// ---- phase B: per-(tv,n) projection, packing, tile binning, sigma reduce ----
__device__ __forceinline__ void preprocess_body(
    const float* __restrict__ center, const float* __restrict__ scale,
    const float* __restrict__ feat, const float* __restrict__ opac,
    const float* __restrict__ bg, const float* __restrict__ intr,
    const float* __restrict__ fpose, const float* __restrict__ c2w,
    float* __restrict__ ws, int idx) {
#pragma clang fp contract(off)
  // Nn = 12544 = 49*256, so tv is uniform across the block.
  const int n  = idx % Nn;
  const int tv = idx / Nn;
  const int v  = tv % Vv;
  const int t  = tv / Vv;
  const size_t gi = (size_t)t * Nn + n;   // gaussian params depend on (t,n) only

  float4* WqA = (float4*)(ws + WS_QA);
  float4* WqB = (float4*)(ws + WS_QB);
  float4* WqC = (float4*)(ws + WS_QC);
  float* Wsum = ws + WS_SUM;
  int*   Wcnt = (int*)(ws + WS_CNT);
  int*   Wtcnt = (int*)(ws + WS_TCNT);
  int*   Wlist = (int*)(ws + WS_LIST);

  // ---- w2c = inv(c2w[tv]) via fp64 adjugate (unrolled, register-resident).
  // Rotation is exactly identity here, so the result is exactly [I | -t] —
  // matches the fp32 reference inverse bitwise.
  double m00, m01, m02, m03, m10, m11, m12, m13,
         m20, m21, m22, m23, m30, m31, m32, m33;
  {
    const float* C = c2w + (size_t)tv * 16;
    m00 = C[0];  m01 = C[1];  m02 = C[2];  m03 = C[3];
    m10 = C[4];  m11 = C[5];  m12 = C[6];  m13 = C[7];
    m20 = C[8];  m21 = C[9];  m22 = C[10]; m23 = C[11];
    m30 = C[12]; m31 = C[13]; m32 = C[14]; m33 = C[15];
  }
  const double s0d = m00 * m11 - m10 * m01;
  const double s1d = m00 * m12 - m10 * m02;
  const double s2d = m00 * m13 - m10 * m03;
  const double s3d = m01 * m12 - m11 * m02;
  const double s4d = m01 * m13 - m11 * m03;
  const double s5d = m02 * m13 - m12 * m03;
  const double c5d = m22 * m33 - m32 * m23;
  const double c4d = m21 * m33 - m31 * m23;
  const double c3d = m21 * m32 - m31 * m22;
  const double c2d = m20 * m33 - m30 * m23;
  const double c1d = m20 * m32 - m30 * m22;
  const double c0d = m20 * m31 - m30 * m21;
  const double invdet =
      1.0 / (s0d * c5d - s1d * c4d + s2d * c3d + s3d * c2d - s4d * c1d + s5d * c0d);
  const float M0  = (float)(( m11 * c5d - m12 * c4d + m13 * c3d) * invdet);
  const float M1  = (float)((-m01 * c5d + m02 * c4d - m03 * c3d) * invdet);
  const float M2  = (float)(( m31 * s5d - m32 * s4d + m33 * s3d) * invdet);
  const float M3  = (float)((-m21 * s5d + m22 * s4d - m23 * s3d) * invdet);
  const float M4  = (float)((-m10 * c5d + m12 * c2d - m13 * c1d) * invdet);
  const float M5  = (float)(( m00 * c5d - m02 * c2d + m03 * c1d) * invdet);
  const float M6  = (float)((-m30 * s5d + m32 * s2d - m33 * s1d) * invdet);
  const float M7  = (float)(( m20 * s5d - m22 * s2d + m23 * s1d) * invdet);
  const float M8  = (float)(( m10 * c4d - m11 * c2d + m13 * c0d) * invdet);
  const float M9  = (float)((-m00 * c4d + m01 * c2d - m03 * c0d) * invdet);
  const float M10 = (float)(( m30 * s4d - m31 * s2d + m33 * s0d) * invdet);
  const float M11 = (float)((-m20 * s4d + m21 * s2d - m23 * s0d) * invdet);

  const float c0 = center[gi * 3 + 0], c1 = center[gi * 3 + 1], c2 = center[gi * 3 + 2];
  const float s0 = scale[gi * 3 + 0], s1 = scale[gi * 3 + 1], s2 = scale[gi * 3 + 2];
  const float sf = ((s0 + s1) + s2) / 3.0f;                 // jnp.mean(axis=-1)
  const float colr = fminf(fmaxf(feat[gi * 3 + 0], 0.0f), 1.0f);
  const float colg = fminf(fmaxf(feat[gi * 3 + 1], 0.0f), 1.0f);
  const float colb = fminf(fmaxf(feat[gi * 3 + 2], 0.0f), 1.0f);
  const float base = fminf(fmaxf(opac[gi], 0.0f), 1.0f);
  const float dyn  = fminf(fmaxf(1.0f - bg[gi], 0.0f), 1.0f);
  const float aAll = base;
  const float aDyn = base * dyn;           // <= aAll
  const float aSta = base * (1.0f - dyn);  // <= aAll

  // world = first_pose @ [c,1]  (exact when first_pose == I)
  float wd[4];
  for (int i = 0; i < 4; ++i)
    wd[i] = ((fpose[i * 4 + 0] * c0 + fpose[i * 4 + 1] * c1) + fpose[i * 4 + 2] * c2) +
            fpose[i * 4 + 3] * 1.0f;

  const float cam0 = ((M0 * wd[0] + M1 * wd[1]) + M2  * wd[2]) + M3  * wd[3];
  const float cam1 = ((M4 * wd[0] + M5 * wd[1]) + M6  * wd[2]) + M7  * wd[3];
  const float cam2 = ((M8 * wd[0] + M9 * wd[1]) + M10 * wd[2]) + M11 * wd[3];
  const bool fin = (fabsf(cam0) <= 3.4028235e38f) && (fabsf(cam1) <= 3.4028235e38f) &&
                   (fabsf(cam2) <= 3.4028235e38f);
  const float z = cam2;
  const float fx = intr[v * 4 + 0], fy = intr[v * 4 + 1];
  const float ppx = intr[v * 4 + 2], ppy = intr[v * 4 + 3];

  bool kept = false;
  float u = 0.0f, vv2 = 0.0f, sig = 0.0f;
  if ((z > 0.001f) && fin) {
    u   = cam0 * fx / z + ppx;            // exact op sequence of the reference
    vv2 = cam1 * fy / z + ppy;
    float tsc = (fx + fy) * 0.5f;
    sig = tsc * fabsf(sf);
    sig = sig / fmaxf(z, 0.001f);
    sig = fminf(fmaxf(sig, 0.75f), 10.0f);
    const bool inb = (u >= -3.0f) && (u <= 450.0f) && (vv2 >= -3.0f) && (vv2 <= 226.0f);
    kept = inb && (aAll > 1e-5f);
  }

  if (kept) {
    const int x0 = (int)floorf(u);
    const int y0 = (int)floorf(vv2);
    const float rc = ceilf(sig * 1.5f);   // RADIUS_SCALE
    const int rad = rc < 1.0f ? 1 : (rc > 2.0f ? 2 : (int)rc);
    const int pk = ((x0 + 4) << 16) | ((y0 + 4) << 4) | rad;
    WqA[idx] = make_float4(z, u, vv2, sig);
    WqB[idx] = make_float4(__int_as_float(pk), colr, colg, colb);
    WqC[idx] = make_float4(aAll, aDyn, aSta, 0.0f);
    // ---- scatter binning to 8x8 tiles (bbox interval-overlap) ----
    const int x_lo = x0 - rad, x_hi = x0 + rad;
    const int y_lo = y0 - rad, y_hi = y0 + rad;
    if (x_hi >= 0 && x_lo < Ww && y_hi >= 0 && y_lo < Hh) {
      const int tx_lo = (x_lo > 0 ? x_lo : 0) >> 3;
      const int tx_hi = (x_hi < Ww - 1 ? x_hi : Ww - 1) >> 3;
      const int ty_lo = (y_lo > 0 ? y_lo : 0) >> 3;
      const int ty_hi = (y_hi < Hh - 1 ? y_hi : Hh - 1) >> 3;
      for (int ty = ty_lo; ty <= ty_hi; ++ty)
        for (int tx = tx_lo; tx <= tx_hi; ++tx) {
          const int tile = (tv * NTY + ty) * NTX + tx;
          const int slot = atomicAdd(&Wtcnt[tile], 1);
          if (slot < CAP_T) Wlist[(size_t)tile * CAP_T + slot] = n;
        }
    }
  }

  // ---- sigma_mean reduction: wave shuffle -> LDS -> ONE atomic pair per block
  float sred = kept ? sig : 0.0f;
  int   cred = kept ? 1 : 0;
  #pragma unroll
  for (int off = 32; off > 0; off >>= 1) {
    sred += __shfl_down(sred, off, 64);
    cred += __shfl_down(cred, off, 64);
  }
  __shared__ float bsum[4];
  __shared__ int   bcnt[4];
  const int wv = threadIdx.x >> 6;
  if ((threadIdx.x & 63) == 0) { bsum[wv] = sred; bcnt[wv] = cred; }
  __syncthreads();
  if (threadIdx.x == 0) {
    const float ts = ((bsum[0] + bsum[1]) + bsum[2]) + bsum[3];
    const int   tc = bcnt[0] + bcnt[1] + bcnt[2] + bcnt[3];
    if (tc > 0) {
      atomicAdd(&Wsum[tv], ts);
      atomicAdd(&Wcnt[tv], tc);
    }
  }
}

// ---- fused cooperative kernel: zero+copy, grid sync, preprocess ----
__global__ __launch_bounds__(256) void prep_coop_k(
    const float* __restrict__ center, const float* __restrict__ scale,
    const float* __restrict__ feat, const float* __restrict__ opac,
    const float* __restrict__ bg, const float* __restrict__ intr,
    const float* __restrict__ fpose, const float* __restrict__ c2w,
    float* __restrict__ ws, const float4* __restrict__ sem,
    float4* __restrict__ semdst) {
  const int idx = blockIdx.x * 256 + threadIdx.x;
  phaseA_body(sem, semdst, ws, idx);
  cg::this_grid().sync();
  preprocess_body(center, scale, feat, opac, bg, intr, fpose, c2w, ws, idx);
}

// ---- fallback path (if cooperative launch is refused): two plain kernels ----
__global__ __launch_bounds__(256) void init_k(const float4* __restrict__ sem,
                                              float4* __restrict__ dst,
                                              float* __restrict__ ws) {
  const int idx = blockIdx.x * 256 + threadIdx.x;
  phaseA_body(sem, dst, ws, idx);
}

__global__ __launch_bounds__(256) void prep_k(
    const float* __restrict__ center, const float* __restrict__ scale,
    const float* __restrict__ feat, const float* __restrict__ opac,
    const float* __restrict__ bg, const float* __restrict__ intr,
    const float* __restrict__ fpose, const float* __restrict__ c2w,
    float* __restrict__ ws) {
  const int idx = blockIdx.x * 256 + threadIdx.x;
  preprocess_body(center, scale, feat, opac, bg, intr, fpose, c2w, ws, idx);
}

// One wave (64 threads) per 8x8 tile. Single-wave blocks: __syncthreads is
// effectively free, and the cnt<=64 sort is a pure in-register shuffle bitonic.
// Finalize (sigma_mean / touch) is folded in via a device-scope completion
// ticket: the last tile block to finish writes the two scalars.
__global__ __launch_bounds__(64) void raster_k(float* __restrict__ ws,
                                               float* __restrict__ out) {
#pragma clang fp contract(off)
  __shared__ unsigned long long s_key[CAP_T];
  __shared__ float4 sA[64], sB[64], sC[64];

  const int tid = threadIdx.x;   // 0..63
  const int tv  = blockIdx.z;
  const int px  = blockIdx.x * TILE + (tid & 7);
  const int py  = blockIdx.y * TILE + (tid >> 3);
  const float fpx = (float)px, fpy = (float)py;
  const size_t base = (size_t)tv * Nn;

  const float4* WqA = (const float4*)(ws + WS_QA);
  const float4* WqB = (const float4*)(ws + WS_QB);
  const float4* WqC = (const float4*)(ws + WS_QC);
  const float* Wsum = ws + WS_SUM;
  const int*   Wcnt = (const int*)(ws + WS_CNT);
  int* Wtouch  = (int*)(ws + WS_TOUCH);
  int* Wticket = (int*)(ws + WS_TICKET);
  const int* Wtcnt = (const int*)(ws + WS_TCNT);
  const int* Wlist = (const int*)(ws + WS_LIST);

  const int tile = (tv * NTY + blockIdx.y) * NTX + blockIdx.x;
  const int cnt0 = Wtcnt[tile];
  const int cnt  = cnt0 < CAP_T ? cnt0 : CAP_T;
  const int* mylist = Wlist + (size_t)tile * CAP_T;

  float Aall = 0.0f, Adyn = 0.0f, Asta = 0.0f;
  float Ra = 0.0f, Ga = 0.0f, Ba = 0.0f;
  float Rd = 0.0f, Gd = 0.0f, Bd = 0.0f;
  float Rs = 0.0f, Gs = 0.0f, Bs = 0.0f;

  auto composite = [&](int m) {
    for (int j = 0; j < m; ++j) {
      const float4 qb = sB[j];                 // (pk, r, g, b) — LDS broadcast
      const int pk  = __float_as_int(qb.x);
      const int rad = pk & 15;
      const int y0  = ((pk >> 4) & 0xfff) - 4;
      const int x0  = (pk >> 16) - 4;
      if (abs(px - x0) <= rad && abs(py - y0) <= rad) {
        const float4 qa = sA[j];               // (z, u, v, sig)
        const float sg = qa.w;
        const float du = (qa.y - fpx) / sg;
        const float dv = (qa.z - fpy) / sg;
        const float gs = expf(-0.5f * (du * du + dv * dv));
        const float4 qc = sC[j];               // (aAll, aDyn, aSta, 0)
        {  // "all" branch: list membership implies aAll > 1e-5
          const float la = fminf(fmaxf(gs * qc.x, 0.0f), 0.999f);
          const float tr = fminf(fmaxf(1.0f - Aall, 0.0f), 1.0f);
          const float ct = la * tr;
          Ra += qb.y * ct; Ga += qb.z * ct; Ba += qb.w * ct;
          Aall = fminf(fmaxf(Aall + ct, 0.0f), 0.999f);
        }
        if (qc.y > 1e-5f) {
          const float la = fminf(fmaxf(gs * qc.y, 0.0f), 0.999f);
          const float tr = fminf(fmaxf(1.0f - Adyn, 0.0f), 1.0f);
          const float ct = la * tr;
          Rd += qb.y * ct; Gd += qb.z * ct; Bd += qb.w * ct;
          Adyn = fminf(fmaxf(Adyn + ct, 0.0f), 0.999f);
        }
        if (qc.z > 1e-5f) {
          const float la = fminf(fmaxf(gs * qc.z, 0.0f), 0.999f);
          const float tr = fminf(fmaxf(1.0f - Asta, 0.0f), 1.0f);
          const float ct = la * tr;
          Rs += qb.y * ct; Gs += qb.z * ct; Bs += qb.w * ct;
          Asta = fminf(fmaxf(Asta + ct, 0.0f), 0.999f);
        }
      }
    }
  };

  if (cnt <= 64) {
    // ---- in-register wave bitonic on (z_bits, n): no LDS, no barriers.
    // z>0 so float-bit order == value order; index tiebreak == stable argsort.
    unsigned long long key = ~0ULL;
    if (tid < cnt) {
      const unsigned int n = (unsigned int)mylist[tid];
      const float z = ws[WS_QA + 4 * (base + (size_t)n)];  // WqA[.].x
      key = ((unsigned long long)__float_as_uint(z) << 32) | n;
    }
    if (cnt > 1) {
      for (int k = 2; k <= 64; k <<= 1) {
        for (int j = k >> 1; j > 0; j >>= 1) {
          const unsigned long long other = shfl_xor_u64(key, j);
          const bool up = ((tid & k) == 0);
          const bool keep_min = (up == ((tid & j) == 0));
          key = keep_min ? (key < other ? key : other) : (key > other ? key : other);
        }
      }
    }
    if (tid < cnt) {  // lane tid holds rank-tid entry; stage it (3x 16B gather)
      const size_t a = base + (size_t)(int)(key & 0xffffffffULL);
      sA[tid] = WqA[a]; sB[tid] = WqB[a]; sC[tid] = WqC[a];
    }
    __syncthreads();   // single wave: near-free, orders LDS writes->reads
    composite(cnt);
  } else {
    // ---- LDS bitonic over P = next pow2 (<= 256), 64 threads striding ----
    for (int i = tid; i < cnt; i += 64) {
      const unsigned int n = (unsigned int)mylist[i];
      const float z = ws[WS_QA + 4 * (base + (size_t)n)];
      s_key[i] = ((unsigned long long)__float_as_uint(z) << 32) | n;
    }
    int P = 1;
    while (P < cnt) P <<= 1;
    for (int i = cnt + tid; i < P; i += 64) s_key[i] = ~0ULL;
    __syncthreads();
    for (int k = 2; k <= P; k <<= 1) {
      for (int j = k >> 1; j > 0; j >>= 1) {
        for (int i = tid; i < P; i += 64) {
          const int ixj = i ^ j;
          if (ixj > i) {
            const unsigned long long a = s_key[i], b2 = s_key[ixj];
            const bool up = ((i & k) == 0);
            if ((a > b2) == up) { s_key[i] = b2; s_key[ixj] = a; }
          }
        }
        __syncthreads();
      }
    }
    for (int cb = 0; cb < cnt; cb += 64) {
      const int m = min(64, cnt - cb);
      if (tid < m) {
        const size_t a = base + (size_t)(int)(s_key[cb + tid] & 0xffffffffULL);
        sA[tid] = WqA[a]; sB[tid] = WqB[a]; sC[tid] = WqC[a];
      }
      __syncthreads();
      composite(m);
      __syncthreads();
    }
  }

  // ---- write outputs ----
  const size_t pix = (size_t)py * Ww + px;
  const size_t hw  = (size_t)HW;
  const size_t m3  = (size_t)tv * 3;
  out[OFF_RGB_STA + (m3 + 0) * hw + pix] = fminf(fmaxf(Rs, 0.0f), 1.0f);
  out[OFF_RGB_STA + (m3 + 1) * hw + pix] = fminf(fmaxf(Gs, 0.0f), 1.0f);
  out[OFF_RGB_STA + (m3 + 2) * hw + pix] = fminf(fmaxf(Bs, 0.0f), 1.0f);
  out[OFF_RGB_DYN + (m3 + 0) * hw + pix] = fminf(fmaxf(Rd, 0.0f), 1.0f);
  out[OFF_RGB_DYN + (m3 + 1) * hw + pix] = fminf(fmaxf(Gd, 0.0f), 1.0f);
  out[OFF_RGB_DYN + (m3 + 2) * hw + pix] = fminf(fmaxf(Bd, 0.0f), 1.0f);
  out[OFF_RGB_ALL + (m3 + 0) * hw + pix] = fminf(fmaxf(Ra, 0.0f), 1.0f);
  out[OFF_RGB_ALL + (m3 + 1) * hw + pix] = fminf(fmaxf(Ga, 0.0f), 1.0f);
  out[OFF_RGB_ALL + (m3 + 2) * hw + pix] = fminf(fmaxf(Ba, 0.0f), 1.0f);
  out[OFF_AL_STA + (size_t)tv * hw + pix] = fminf(fmaxf(Asta, 0.0f), 1.0f);
  out[OFF_AL_DYN + (size_t)tv * hw + pix] = fminf(fmaxf(Adyn, 0.0f), 1.0f);
  out[OFF_AL_ALL + (size_t)tv * hw + pix] = fminf(fmaxf(Aall, 0.0f), 1.0f);

  // ---- fused finalize: touch popcount via one atomic per tile, then the
  // last block through the ticket computes the two scalar outputs. ----
  const unsigned long long bal = __ballot(Aall > 1e-6f);
  if (tid == 0) {
    atomicAdd(Wtouch, (int)__popcll(bal));
    __threadfence();                          // touch-add visible before ticket
    const int done = atomicAdd(Wticket, 1);
    if (done == NTILES - 1) {                 // all tiles' adds are visible now
      __threadfence();
      float sm = 0.0f;
      for (int i = 0; i < TV; ++i) {
        const int c = Wcnt[i];
        sm += (c > 0) ? (Wsum[i] / (float)(c > 1 ? c : 1)) : 0.0f;
      }
      const int grand = atomicAdd(Wtouch, 0); // coherent read
      out[OFF_SM]    = sm / (float)TV;
      out[OFF_TOUCH] = (float)grand / (float)(HW * TV);
    }
  }
}

extern "C" void kernel_launch(void* const* d_in, const int* in_sizes, int n_in,
                              void* d_out, int out_size, void* d_ws, size_t ws_size,
                              hipStream_t stream) {
  const float* center = (const float*)d_in[0];
  const float* scale  = (const float*)d_in[1];
  const float* feat   = (const float*)d_in[2];
  const float* opac   = (const float*)d_in[3];
  const float* bg     = (const float*)d_in[4];
  const float* sem    = (const float*)d_in[5];
  const float* intr   = (const float*)d_in[6];
  const float* c2w    = (const float*)d_in[7];
  const float* fpose  = (const float*)d_in[8];
  float* out = (float*)d_out;
  float* ws  = (float*)d_ws;
  const float4* sem4 = (const float4*)sem;
  float4* semdst = (float4*)(out + OFF_SEM);

  // Fused init+preprocess: 196 blocks x 256 — trivially co-resident on 256 CUs.
  void* args[] = {(void*)&center, (void*)&scale, (void*)&feat, (void*)&opac,
                  (void*)&bg,     (void*)&intr,  (void*)&fpose, (void*)&c2w,
                  (void*)&ws,     (void*)&sem4,  (void*)&semdst};
  const hipError_t ce = hipLaunchCooperativeKernel(
      reinterpret_cast<const void*>(&prep_coop_k), dim3(TOT / 256), dim3(256),
      args, 0, stream);
  if (ce != hipSuccess) {
    (void)hipGetLastError();  // clear sticky error; fall back to 2 plain launches
    hipLaunchKernelGGL(init_k, dim3(TOT / 256), dim3(256), 0, stream,
                       sem4, semdst, ws);
    hipLaunchKernelGGL(prep_k, dim3(TOT / 256), dim3(256), 0, stream,
                       center, scale, feat, opac, bg, intr, fpose, c2w, ws);
  }
  hipLaunchKernelGGL(raster_k, dim3(NTX, NTY, TV), dim3(64), 0, stream, ws, out);
}

// Round 2
// 239.311 us; speedup vs baseline: 1.4831x; 1.4831x over previous
//
#include <hip/hip_runtime.h>
#include <cmath>

namespace {
constexpr int Hh = 224, Ww = 448;
constexpr int Tt = 2, Vv = 2, GH = 56, GW = 112;
constexpr int Nn = Vv * GH * GW;       // 12544 gaussians per (t) set
constexpr int TV = Tt * Vv;            // 4 render views
constexpr int TOT = TV * Nn;           // 50176 (view,gaussian) pairs
constexpr int HW = Hh * Ww;            // 100352
constexpr int TILE = 8;                // 8x8 tiles, one wave per tile
constexpr int NTX = Ww / TILE;         // 56
constexpr int NTY = Hh / TILE;         // 28
constexpr int NTILES = TV * NTX * NTY; // 6272
constexpr int CAP_T = 256;             // per-tile list capacity (expected peak ~80)

constexpr size_t RGB_SZ = (size_t)TV * 3 * HW;   // 1204224
constexpr size_t AL_SZ  = (size_t)TV * HW;       // 401408
constexpr size_t OFF_RGB_STA = 0;
constexpr size_t OFF_RGB_DYN = RGB_SZ;
constexpr size_t OFF_RGB_ALL = 2 * RGB_SZ;
constexpr size_t OFF_AL_STA  = 3 * RGB_SZ;
constexpr size_t OFF_AL_DYN  = 3 * RGB_SZ + AL_SZ;
constexpr size_t OFF_AL_ALL  = 3 * RGB_SZ + 2 * AL_SZ;
constexpr size_t OFF_SEM     = 3 * RGB_SZ + 3 * AL_SZ;
constexpr size_t OFF_SM      = OFF_SEM + RGB_SZ;
constexpr size_t OFF_TOUCH   = OFF_SM + 1;

// ---- ws layout (floats) ----
// Packed per-(tv,n) gaussian records, 3 float4 arrays:
//   QA = (z, u, v, sig) | QB = (pk_bits, r, g, b) | QC = (aAll, aDyn, aSta, 0)
// then: 4 f sum_sigma | 4 i cnt | 1 i touch-acc | 1 i ticket |
//       NTILES i tile-counters | NTILES*CAP_T i tile lists
constexpr size_t WS_QA   = 0;
constexpr size_t WS_QB   = (size_t)4 * TOT;
constexpr size_t WS_QC   = (size_t)8 * TOT;
constexpr size_t WS_SUM  = (size_t)12 * TOT;
constexpr size_t WS_CNT  = WS_SUM + 4;
constexpr size_t WS_TOUCH  = WS_CNT + 4;
constexpr size_t WS_TICKET = WS_TOUCH + 1;
constexpr size_t WS_TCNT = WS_TICKET + 1;
constexpr size_t WS_LIST = WS_TCNT + NTILES;
constexpr int    N_ZERO  = 10 + NTILES;  // Wsum+Wcnt+touch+ticket+Wtcnt
} // namespace

__device__ inline unsigned long long shfl_xor_u64(unsigned long long x, int m) {
  unsigned int lo = (unsigned int)x, hi = (unsigned int)(x >> 32);
  lo = __shfl_xor(lo, m, 64);
  hi = __shfl_xor(hi, m, 64);
  return ((unsigned long long)hi << 32) | lo;
}

// sem copy + zero the counter region. NO fences anywhere in this pipeline:
// per-block agent-scope cache maintenance (threadfence / grid.sync) costs
// ~L2-writeback per block and was the round-1 5x regression.
__global__ __launch_bounds__(256) void init_k(const float4* __restrict__ sem,
                                              float4* __restrict__ dst,
                                              float* __restrict__ ws) {
  const int i = blockIdx.x * 256 + threadIdx.x;
  if (i < (int)(RGB_SZ / 4)) dst[i] = sem[i];
  if (blockIdx.x == gridDim.x - 1) {
    int* W = (int*)(ws + WS_SUM);
    for (int k = threadIdx.x; k < N_ZERO; k += 256) W[k] = 0;
  }
}

__global__ __launch_bounds__(256) void prep_k(
    const float* __restrict__ center, const float* __restrict__ scale,
    const float* __restrict__ feat, const float* __restrict__ opac,
    const float* __restrict__ bg, const float* __restrict__ intr,
    const float* __restrict__ fpose, const float* __restrict__ c2w,
    float* __restrict__ ws) {
#pragma clang fp contract(off)
  const int idx = blockIdx.x * 256 + threadIdx.x;
  // Nn = 12544 = 49*256, so tv is uniform across the block.
  const int n  = idx % Nn;
  const int tv = idx / Nn;
  const int v  = tv % Vv;
  const int t  = tv / Vv;
  const size_t gi = (size_t)t * Nn + n;   // gaussian params depend on (t,n) only

  float4* WqA = (float4*)(ws + WS_QA);
  float4* WqB = (float4*)(ws + WS_QB);
  float4* WqC = (float4*)(ws + WS_QC);
  float* Wsum = ws + WS_SUM;
  int*   Wcnt = (int*)(ws + WS_CNT);
  int*   Wtcnt = (int*)(ws + WS_TCNT);
  int*   Wlist = (int*)(ws + WS_LIST);

  // ---- w2c = inv(c2w[tv]) via fp64 adjugate (unrolled, register-resident).
  // Rotation is exactly identity here, so the result is exactly [I | -t] —
  // matches the fp32 reference inverse bitwise.
  double m00, m01, m02, m03, m10, m11, m12, m13,
         m20, m21, m22, m23, m30, m31, m32, m33;
  {
    const float* C = c2w + (size_t)tv * 16;
    m00 = C[0];  m01 = C[1];  m02 = C[2];  m03 = C[3];
    m10 = C[4];  m11 = C[5];  m12 = C[6];  m13 = C[7];
    m20 = C[8];  m21 = C[9];  m22 = C[10]; m23 = C[11];
    m30 = C[12]; m31 = C[13]; m32 = C[14]; m33 = C[15];
  }
  const double s0d = m00 * m11 - m10 * m01;
  const double s1d = m00 * m12 - m10 * m02;
  const double s2d = m00 * m13 - m10 * m03;
  const double s3d = m01 * m12 - m11 * m02;
  const double s4d = m01 * m13 - m11 * m03;
  const double s5d = m02 * m13 - m12 * m03;
  const double c5d = m22 * m33 - m32 * m23;
  const double c4d = m21 * m33 - m31 * m23;
  const double c3d = m21 * m32 - m31 * m22;
  const double c2d = m20 * m33 - m30 * m23;
  const double c1d = m20 * m32 - m30 * m22;
  const double c0d = m20 * m31 - m30 * m21;
  const double invdet =
      1.0 / (s0d * c5d - s1d * c4d + s2d * c3d + s3d * c2d - s4d * c1d + s5d * c0d);
  const float M0  = (float)(( m11 * c5d - m12 * c4d + m13 * c3d) * invdet);
  const float M1  = (float)((-m01 * c5d + m02 * c4d - m03 * c3d) * invdet);
  const float M2  = (float)(( m31 * s5d - m32 * s4d + m33 * s3d) * invdet);
  const float M3  = (float)((-m21 * s5d + m22 * s4d - m23 * s3d) * invdet);
  const float M4  = (float)((-m10 * c5d + m12 * c2d - m13 * c1d) * invdet);
  const float M5  = (float)(( m00 * c5d - m02 * c2d + m03 * c1d) * invdet);
  const float M6  = (float)((-m30 * s5d + m32 * s2d - m33 * s1d) * invdet);
  const float M7  = (float)(( m20 * s5d - m22 * s2d + m23 * s1d) * invdet);
  const float M8  = (float)(( m10 * c4d - m11 * c2d + m13 * c0d) * invdet);
  const float M9  = (float)((-m00 * c4d + m01 * c2d - m03 * c0d) * invdet);
  const float M10 = (float)(( m30 * s4d - m31 * s2d + m33 * s0d) * invdet);
  const float M11 = (float)((-m20 * s4d + m21 * s2d - m23 * s0d) * invdet);

  const float c0 = center[gi * 3 + 0], c1 = center[gi * 3 + 1], c2 = center[gi * 3 + 2];
  const float s0 = scale[gi * 3 + 0], s1 = scale[gi * 3 + 1], s2 = scale[gi * 3 + 2];
  const float sf = ((s0 + s1) + s2) / 3.0f;                 // jnp.mean(axis=-1)
  const float colr = fminf(fmaxf(feat[gi * 3 + 0], 0.0f), 1.0f);
  const float colg = fminf(fmaxf(feat[gi * 3 + 1], 0.0f), 1.0f);
  const float colb = fminf(fmaxf(feat[gi * 3 + 2], 0.0f), 1.0f);
  const float base = fminf(fmaxf(opac[gi], 0.0f), 1.0f);
  const float dyn  = fminf(fmaxf(1.0f - bg[gi], 0.0f), 1.0f);
  const float aAll = base;
  const float aDyn = base * dyn;           // <= aAll
  const float aSta = base * (1.0f - dyn);  // <= aAll

  // world = first_pose @ [c,1]  (exact when first_pose == I)
  float wd[4];
  for (int i = 0; i < 4; ++i)
    wd[i] = ((fpose[i * 4 + 0] * c0 + fpose[i * 4 + 1] * c1) + fpose[i * 4 + 2] * c2) +
            fpose[i * 4 + 3] * 1.0f;

  const float cam0 = ((M0 * wd[0] + M1 * wd[1]) + M2  * wd[2]) + M3  * wd[3];
  const float cam1 = ((M4 * wd[0] + M5 * wd[1]) + M6  * wd[2]) + M7  * wd[3];
  const float cam2 = ((M8 * wd[0] + M9 * wd[1]) + M10 * wd[2]) + M11 * wd[3];
  const bool fin = (fabsf(cam0) <= 3.4028235e38f) && (fabsf(cam1) <= 3.4028235e38f) &&
                   (fabsf(cam2) <= 3.4028235e38f);
  const float z = cam2;
  const float fx = intr[v * 4 + 0], fy = intr[v * 4 + 1];
  const float ppx = intr[v * 4 + 2], ppy = intr[v * 4 + 3];

  bool kept = false;
  float u = 0.0f, vv2 = 0.0f, sig = 0.0f;
  if ((z > 0.001f) && fin) {
    u   = cam0 * fx / z + ppx;            // exact op sequence of the reference
    vv2 = cam1 * fy / z + ppy;
    float tsc = (fx + fy) * 0.5f;
    sig = tsc * fabsf(sf);
    sig = sig / fmaxf(z, 0.001f);
    sig = fminf(fmaxf(sig, 0.75f), 10.0f);
    const bool inb = (u >= -3.0f) && (u <= 450.0f) && (vv2 >= -3.0f) && (vv2 <= 226.0f);
    kept = inb && (aAll > 1e-5f);
  }

  if (kept) {
    const int x0 = (int)floorf(u);
    const int y0 = (int)floorf(vv2);
    const float rc = ceilf(sig * 1.5f);   // RADIUS_SCALE
    const int rad = rc < 1.0f ? 1 : (rc > 2.0f ? 2 : (int)rc);
    const int pk = ((x0 + 4) << 16) | ((y0 + 4) << 4) | rad;
    WqA[idx] = make_float4(z, u, vv2, sig);
    WqB[idx] = make_float4(__int_as_float(pk), colr, colg, colb);
    WqC[idx] = make_float4(aAll, aDyn, aSta, 0.0f);
    // ---- scatter binning to 8x8 tiles (bbox interval-overlap) ----
    const int x_lo = x0 - rad, x_hi = x0 + rad;
    const int y_lo = y0 - rad, y_hi = y0 + rad;
    if (x_hi >= 0 && x_lo < Ww && y_hi >= 0 && y_lo < Hh) {
      const int tx_lo = (x_lo > 0 ? x_lo : 0) >> 3;
      const int tx_hi = (x_hi < Ww - 1 ? x_hi : Ww - 1) >> 3;
      const int ty_lo = (y_lo > 0 ? y_lo : 0) >> 3;
      const int ty_hi = (y_hi < Hh - 1 ? y_hi : Hh - 1) >> 3;
      for (int ty = ty_lo; ty <= ty_hi; ++ty)
        for (int tx = tx_lo; tx <= tx_hi; ++tx) {
          const int tile = (tv * NTY + ty) * NTX + tx;
          const int slot = atomicAdd(&Wtcnt[tile], 1);
          if (slot < CAP_T) Wlist[(size_t)tile * CAP_T + slot] = n;
        }
    }
  }

  // ---- sigma_mean reduction: wave shuffle -> LDS -> ONE atomic pair per block
  float sred = kept ? sig : 0.0f;
  int   cred = kept ? 1 : 0;
  #pragma unroll
  for (int off = 32; off > 0; off >>= 1) {
    sred += __shfl_down(sred, off, 64);
    cred += __shfl_down(cred, off, 64);
  }
  __shared__ float bsum[4];
  __shared__ int   bcnt[4];
  const int wv = threadIdx.x >> 6;
  if ((threadIdx.x & 63) == 0) { bsum[wv] = sred; bcnt[wv] = cred; }
  __syncthreads();
  if (threadIdx.x == 0) {
    const float ts = ((bsum[0] + bsum[1]) + bsum[2]) + bsum[3];
    const int   tc = bcnt[0] + bcnt[1] + bcnt[2] + bcnt[3];
    if (tc > 0) {
      atomicAdd(&Wsum[tv], ts);
      atomicAdd(&Wcnt[tv], tc);
    }
  }
}

// One wave (64 threads) per 8x8 tile. Single-wave blocks: __syncthreads is
// effectively free, and the cnt<=64 sort is a pure in-register shuffle bitonic.
// Finalize is fused via FENCE-FREE relaxed atomics: atomic RMWs execute at the
// device coherent point, so ordering only needs "my touch-add completed before
// my ticket-add issues" — enforced with a raw s_waitcnt vmcnt(0) (no L2
// writeback, unlike __threadfence, which caused the round-1 5x regression).
__global__ __launch_bounds__(64) void raster_k(float* __restrict__ ws,
                                               float* __restrict__ out) {
#pragma clang fp contract(off)
  __shared__ unsigned long long s_key[CAP_T];
  __shared__ float4 sA[64], sB[64], sC[64];

  const int tid = threadIdx.x;   // 0..63
  const int tv  = blockIdx.z;
  const int px  = blockIdx.x * TILE + (tid & 7);
  const int py  = blockIdx.y * TILE + (tid >> 3);
  const float fpx = (float)px, fpy = (float)py;
  const size_t base = (size_t)tv * Nn;

  const float4* WqA = (const float4*)(ws + WS_QA);
  const float4* WqB = (const float4*)(ws + WS_QB);
  const float4* WqC = (const float4*)(ws + WS_QC);
  const float* Wsum = ws + WS_SUM;
  const int*   Wcnt = (const int*)(ws + WS_CNT);
  int* Wtouch  = (int*)(ws + WS_TOUCH);
  int* Wticket = (int*)(ws + WS_TICKET);
  const int* Wtcnt = (const int*)(ws + WS_TCNT);
  const int* Wlist = (const int*)(ws + WS_LIST);

  const int tile = (tv * NTY + blockIdx.y) * NTX + blockIdx.x;
  const int cnt0 = Wtcnt[tile];
  const int cnt  = cnt0 < CAP_T ? cnt0 : CAP_T;
  const int* mylist = Wlist + (size_t)tile * CAP_T;

  float Aall = 0.0f, Adyn = 0.0f, Asta = 0.0f;
  float Ra = 0.0f, Ga = 0.0f, Ba = 0.0f;
  float Rd = 0.0f, Gd = 0.0f, Bd = 0.0f;
  float Rs = 0.0f, Gs = 0.0f, Bs = 0.0f;

  auto composite = [&](int m) {
    for (int j = 0; j < m; ++j) {
      const float4 qb = sB[j];                 // (pk, r, g, b) — LDS broadcast
      const int pk  = __float_as_int(qb.x);
      const int rad = pk & 15;
      const int y0  = ((pk >> 4) & 0xfff) - 4;
      const int x0  = (pk >> 16) - 4;
      if (abs(px - x0) <= rad && abs(py - y0) <= rad) {
        const float4 qa = sA[j];               // (z, u, v, sig)
        const float sg = qa.w;
        const float du = (qa.y - fpx) / sg;
        const float dv = (qa.z - fpy) / sg;
        const float gs = expf(-0.5f * (du * du + dv * dv));
        const float4 qc = sC[j];               // (aAll, aDyn, aSta, 0)
        {  // "all" branch: list membership implies aAll > 1e-5
          const float la = fminf(fmaxf(gs * qc.x, 0.0f), 0.999f);
          const float tr = fminf(fmaxf(1.0f - Aall, 0.0f), 1.0f);
          const float ct = la * tr;
          Ra += qb.y * ct; Ga += qb.z * ct; Ba += qb.w * ct;
          Aall = fminf(fmaxf(Aall + ct, 0.0f), 0.999f);
        }
        if (qc.y > 1e-5f) {
          const float la = fminf(fmaxf(gs * qc.y, 0.0f), 0.999f);
          const float tr = fminf(fmaxf(1.0f - Adyn, 0.0f), 1.0f);
          const float ct = la * tr;
          Rd += qb.y * ct; Gd += qb.z * ct; Bd += qb.w * ct;
          Adyn = fminf(fmaxf(Adyn + ct, 0.0f), 0.999f);
        }
        if (qc.z > 1e-5f) {
          const float la = fminf(fmaxf(gs * qc.z, 0.0f), 0.999f);
          const float tr = fminf(fmaxf(1.0f - Asta, 0.0f), 1.0f);
          const float ct = la * tr;
          Rs += qb.y * ct; Gs += qb.z * ct; Bs += qb.w * ct;
          Asta = fminf(fmaxf(Asta + ct, 0.0f), 0.999f);
        }
      }
    }
  };

  if (cnt <= 64) {
    // ---- in-register wave bitonic on (z_bits, n): no LDS, no barriers.
    // z>0 so float-bit order == value order; index tiebreak == stable argsort.
    unsigned long long key = ~0ULL;
    if (tid < cnt) {
      const unsigned int n = (unsigned int)mylist[tid];
      const float z = ws[WS_QA + 4 * (base + (size_t)n)];  // WqA[.].x
      key = ((unsigned long long)__float_as_uint(z) << 32) | n;
    }
    if (cnt > 1) {
      for (int k = 2; k <= 64; k <<= 1) {
        for (int j = k >> 1; j > 0; j >>= 1) {
          const unsigned long long other = shfl_xor_u64(key, j);
          const bool up = ((tid & k) == 0);
          const bool keep_min = (up == ((tid & j) == 0));
          key = keep_min ? (key < other ? key : other) : (key > other ? key : other);
        }
      }
    }
    if (tid < cnt) {  // lane tid holds rank-tid entry; stage it (3x 16B gather)
      const size_t a = base + (size_t)(int)(key & 0xffffffffULL);
      sA[tid] = WqA[a]; sB[tid] = WqB[a]; sC[tid] = WqC[a];
    }
    __syncthreads();   // single wave: near-free, orders LDS writes->reads
    composite(cnt);
  } else {
    // ---- LDS bitonic over P = next pow2 (<= 256), 64 threads striding ----
    for (int i = tid; i < cnt; i += 64) {
      const unsigned int n = (unsigned int)mylist[i];
      const float z = ws[WS_QA + 4 * (base + (size_t)n)];
      s_key[i] = ((unsigned long long)__float_as_uint(z) << 32) | n;
    }
    int P = 1;
    while (P < cnt) P <<= 1;
    for (int i = cnt + tid; i < P; i += 64) s_key[i] = ~0ULL;
    __syncthreads();
    for (int k = 2; k <= P; k <<= 1) {
      for (int j = k >> 1; j > 0; j >>= 1) {
        for (int i = tid; i < P; i += 64) {
          const int ixj = i ^ j;
          if (ixj > i) {
            const unsigned long long a = s_key[i], b2 = s_key[ixj];
            const bool up = ((i & k) == 0);
            if ((a > b2) == up) { s_key[i] = b2; s_key[ixj] = a; }
          }
        }
        __syncthreads();
      }
    }
    for (int cb = 0; cb < cnt; cb += 64) {
      const int m = min(64, cnt - cb);
      if (tid < m) {
        const size_t a = base + (size_t)(int)(s_key[cb + tid] & 0xffffffffULL);
        sA[tid] = WqA[a]; sB[tid] = WqB[a]; sC[tid] = WqC[a];
      }
      __syncthreads();
      composite(m);
      __syncthreads();
    }
  }

  // ---- write outputs ----
  const size_t pix = (size_t)py * Ww + px;
  const size_t hw  = (size_t)HW;
  const size_t m3  = (size_t)tv * 3;
  out[OFF_RGB_STA + (m3 + 0) * hw + pix] = fminf(fmaxf(Rs, 0.0f), 1.0f);
  out[OFF_RGB_STA + (m3 + 1) * hw + pix] = fminf(fmaxf(Gs, 0.0f), 1.0f);
  out[OFF_RGB_STA + (m3 + 2) * hw + pix] = fminf(fmaxf(Bs, 0.0f), 1.0f);
  out[OFF_RGB_DYN + (m3 + 0) * hw + pix] = fminf(fmaxf(Rd, 0.0f), 1.0f);
  out[OFF_RGB_DYN + (m3 + 1) * hw + pix] = fminf(fmaxf(Gd, 0.0f), 1.0f);
  out[OFF_RGB_DYN + (m3 + 2) * hw + pix] = fminf(fmaxf(Bd, 0.0f), 1.0f);
  out[OFF_RGB_ALL + (m3 + 0) * hw + pix] = fminf(fmaxf(Ra, 0.0f), 1.0f);
  out[OFF_RGB_ALL + (m3 + 1) * hw + pix] = fminf(fmaxf(Ga, 0.0f), 1.0f);
  out[OFF_RGB_ALL + (m3 + 2) * hw + pix] = fminf(fmaxf(Ba, 0.0f), 1.0f);
  out[OFF_AL_STA + (size_t)tv * hw + pix] = fminf(fmaxf(Asta, 0.0f), 1.0f);
  out[OFF_AL_DYN + (size_t)tv * hw + pix] = fminf(fmaxf(Adyn, 0.0f), 1.0f);
  out[OFF_AL_ALL + (size_t)tv * hw + pix] = fminf(fmaxf(Aall, 0.0f), 1.0f);

  // ---- fused finalize, fence-free ----
  const unsigned long long bal = __ballot(Aall > 1e-6f);
  if (tid == 0) {
    const int pc = (int)__popcll(bal);
    (void)atomicAdd(Wtouch, pc);                  // RMW at coherent point
    // Ensure the touch-add has completed (acked) before the ticket-add is
    // issued. Raw vmcnt wait: no cache writeback, unlike __threadfence.
    asm volatile("s_waitcnt vmcnt(0)" ::: "memory");
    const int done = atomicAdd(Wticket, 1);
    if (done == NTILES - 1) {
      // Every other block's ticket-add followed its completed touch-add,
      // so all touch contributions are visible at the coherent point.
      const int grand = atomicAdd(Wtouch, 0);     // coherent read
      float sm = 0.0f;
      for (int i = 0; i < TV; ++i) {
        const int c = Wcnt[i];   // written by prep_k: kernel-boundary ordered
        sm += (c > 0) ? (Wsum[i] / (float)(c > 1 ? c : 1)) : 0.0f;
      }
      out[OFF_SM]    = sm / (float)TV;
      out[OFF_TOUCH] = (float)grand / (float)(HW * TV);
    }
  }
}

extern "C" void kernel_launch(void* const* d_in, const int* in_sizes, int n_in,
                              void* d_out, int out_size, void* d_ws, size_t ws_size,
                              hipStream_t stream) {
  const float* center = (const float*)d_in[0];
  const float* scale  = (const float*)d_in[1];
  const float* feat   = (const float*)d_in[2];
  const float* opac   = (const float*)d_in[3];
  const float* bg     = (const float*)d_in[4];
  const float* sem    = (const float*)d_in[5];
  const float* intr   = (const float*)d_in[6];
  const float* c2w    = (const float*)d_in[7];
  const float* fpose  = (const float*)d_in[8];
  float* out = (float*)d_out;
  float* ws  = (float*)d_ws;

  const int copy_blocks = (int)((RGB_SZ / 4 + 255) / 256) + 1;  // last block zeroes
  hipLaunchKernelGGL(init_k, dim3(copy_blocks), dim3(256), 0, stream,
                     (const float4*)sem, (float4*)(out + OFF_SEM), ws);
  hipLaunchKernelGGL(prep_k, dim3(TOT / 256), dim3(256), 0, stream,
                     center, scale, feat, opac, bg, intr, fpose, c2w, ws);
  hipLaunchKernelGGL(raster_k, dim3(NTX, NTY, TV), dim3(64), 0, stream, ws, out);
}

// Round 3
// 125.472 us; speedup vs baseline: 2.8287x; 1.9073x over previous
//
#include <hip/hip_runtime.h>
#include <cmath>

namespace {
constexpr int Hh = 224, Ww = 448;
constexpr int Tt = 2, Vv = 2, GH = 56, GW = 112;
constexpr int Nn = Vv * GH * GW;       // 12544 gaussians per (t) set
constexpr int TV = Tt * Vv;            // 4 render views
constexpr int TOT = TV * Nn;           // 50176 (view,gaussian) pairs
constexpr int HW = Hh * Ww;            // 100352
constexpr int TILE = 8;                // 8x8 tiles, one wave per tile
constexpr int NTX = Ww / TILE;         // 56
constexpr int NTY = Hh / TILE;         // 28
constexpr int NTILES = TV * NTX * NTY; // 6272
constexpr int CAP_T = 256;             // per-tile list capacity (expected peak ~80)
constexpr int NGRP = NTILES / 64;      // 98 exact groups of 64 tiles

constexpr size_t RGB_SZ = (size_t)TV * 3 * HW;   // 1204224
constexpr size_t AL_SZ  = (size_t)TV * HW;       // 401408
constexpr size_t OFF_RGB_STA = 0;
constexpr size_t OFF_RGB_DYN = RGB_SZ;
constexpr size_t OFF_RGB_ALL = 2 * RGB_SZ;
constexpr size_t OFF_AL_STA  = 3 * RGB_SZ;
constexpr size_t OFF_AL_DYN  = 3 * RGB_SZ + AL_SZ;
constexpr size_t OFF_AL_ALL  = 3 * RGB_SZ + 2 * AL_SZ;
constexpr size_t OFF_SEM     = 3 * RGB_SZ + 3 * AL_SZ;
constexpr size_t OFF_SM      = OFF_SEM + RGB_SZ;
constexpr size_t OFF_TOUCH   = OFF_SM + 1;

// ---- ws layout (floats) ----
// Packed per-(tv,n) gaussian records, 3 float4 arrays:
//   QA = (z, u, v, sig) | QB = (pk_bits, r, g, b) | QC = (aAll, aDyn, aSta, 0)
// then: 4 f sum_sigma | 4 i cnt | 2 w u64 global (count<<32 | touch) |
//       NGRP i group (count<<16 | touch) | NTILES i tile-counters |
//       NTILES*CAP_T i tile lists
constexpr size_t WS_QA   = 0;
constexpr size_t WS_QB   = (size_t)4 * TOT;
constexpr size_t WS_QC   = (size_t)8 * TOT;
constexpr size_t WS_SUM  = (size_t)12 * TOT;   // word offset; *4 bytes is 8B-aligned
constexpr size_t WS_CNT  = WS_SUM + 4;
constexpr size_t WS_GLB  = WS_CNT + 4;         // u64, 8B aligned (offset even)
constexpr size_t WS_GRP  = WS_GLB + 2;
constexpr size_t WS_TCNT = WS_GRP + NGRP;
constexpr size_t WS_LIST = WS_TCNT + NTILES;
constexpr int    N_ZERO  = 10 + NGRP + NTILES;  // Wsum+Wcnt+glb+grp+Wtcnt
} // namespace

__device__ inline unsigned long long shfl_xor_u64(unsigned long long x, int m) {
  unsigned int lo = (unsigned int)x, hi = (unsigned int)(x >> 32);
  lo = __shfl_xor(lo, m, 64);
  hi = __shfl_xor(hi, m, 64);
  return ((unsigned long long)hi << 32) | lo;
}

// sem copy + zero the counter region. NO fences anywhere in this pipeline:
// per-block agent-scope cache maintenance (threadfence / grid.sync) costs
// ~L2-writeback per block and was the round-1 5x regression.
__global__ __launch_bounds__(256) void init_k(const float4* __restrict__ sem,
                                              float4* __restrict__ dst,
                                              float* __restrict__ ws) {
  const int i = blockIdx.x * 256 + threadIdx.x;
  if (i < (int)(RGB_SZ / 4)) dst[i] = sem[i];
  if (blockIdx.x == gridDim.x - 1) {
    int* W = (int*)(ws + WS_SUM);
    for (int k = threadIdx.x; k < N_ZERO; k += 256) W[k] = 0;
  }
}

__global__ __launch_bounds__(256) void prep_k(
    const float* __restrict__ center, const float* __restrict__ scale,
    const float* __restrict__ feat, const float* __restrict__ opac,
    const float* __restrict__ bg, const float* __restrict__ intr,
    const float* __restrict__ fpose, const float* __restrict__ c2w,
    float* __restrict__ ws) {
#pragma clang fp contract(off)
  const int idx = blockIdx.x * 256 + threadIdx.x;
  // Nn = 12544 = 49*256, so tv is uniform across the block.
  const int n  = idx % Nn;
  const int tv = idx / Nn;
  const int v  = tv % Vv;
  const int t  = tv / Vv;
  const size_t gi = (size_t)t * Nn + n;   // gaussian params depend on (t,n) only

  float4* WqA = (float4*)(ws + WS_QA);
  float4* WqB = (float4*)(ws + WS_QB);
  float4* WqC = (float4*)(ws + WS_QC);
  float* Wsum = ws + WS_SUM;
  int*   Wcnt = (int*)(ws + WS_CNT);
  int*   Wtcnt = (int*)(ws + WS_TCNT);
  int*   Wlist = (int*)(ws + WS_LIST);

  // ---- w2c = inv(c2w[tv]) via fp64 adjugate (unrolled, register-resident).
  // Rotation is exactly identity here, so the result is exactly [I | -t] —
  // matches the fp32 reference inverse bitwise.
  double m00, m01, m02, m03, m10, m11, m12, m13,
         m20, m21, m22, m23, m30, m31, m32, m33;
  {
    const float* C = c2w + (size_t)tv * 16;
    m00 = C[0];  m01 = C[1];  m02 = C[2];  m03 = C[3];
    m10 = C[4];  m11 = C[5];  m12 = C[6];  m13 = C[7];
    m20 = C[8];  m21 = C[9];  m22 = C[10]; m23 = C[11];
    m30 = C[12]; m31 = C[13]; m32 = C[14]; m33 = C[15];
  }
  const double s0d = m00 * m11 - m10 * m01;
  const double s1d = m00 * m12 - m10 * m02;
  const double s2d = m00 * m13 - m10 * m03;
  const double s3d = m01 * m12 - m11 * m02;
  const double s4d = m01 * m13 - m11 * m03;
  const double s5d = m02 * m13 - m12 * m03;
  const double c5d = m22 * m33 - m32 * m23;
  const double c4d = m21 * m33 - m31 * m23;
  const double c3d = m21 * m32 - m31 * m22;
  const double c2d = m20 * m33 - m30 * m23;
  const double c1d = m20 * m32 - m30 * m22;
  const double c0d = m20 * m31 - m30 * m21;
  const double invdet =
      1.0 / (s0d * c5d - s1d * c4d + s2d * c3d + s3d * c2d - s4d * c1d + s5d * c0d);
  const float M0  = (float)(( m11 * c5d - m12 * c4d + m13 * c3d) * invdet);
  const float M1  = (float)((-m01 * c5d + m02 * c4d - m03 * c3d) * invdet);
  const float M2  = (float)(( m31 * s5d - m32 * s4d + m33 * s3d) * invdet);
  const float M3  = (float)((-m21 * s5d + m22 * s4d - m23 * s3d) * invdet);
  const float M4  = (float)((-m10 * c5d + m12 * c2d - m13 * c1d) * invdet);
  const float M5  = (float)(( m00 * c5d - m02 * c2d + m03 * c1d) * invdet);
  const float M6  = (float)((-m30 * s5d + m32 * s2d - m33 * s1d) * invdet);
  const float M7  = (float)(( m20 * s5d - m22 * s2d + m23 * s1d) * invdet);
  const float M8  = (float)(( m10 * c4d - m11 * c2d + m13 * c0d) * invdet);
  const float M9  = (float)((-m00 * c4d + m01 * c2d - m03 * c0d) * invdet);
  const float M10 = (float)(( m30 * s4d - m31 * s2d + m33 * s0d) * invdet);
  const float M11 = (float)((-m20 * s4d + m21 * s2d - m23 * s0d) * invdet);

  const float c0 = center[gi * 3 + 0], c1 = center[gi * 3 + 1], c2 = center[gi * 3 + 2];
  const float s0 = scale[gi * 3 + 0], s1 = scale[gi * 3 + 1], s2 = scale[gi * 3 + 2];
  const float sf = ((s0 + s1) + s2) / 3.0f;                 // jnp.mean(axis=-1)
  const float colr = fminf(fmaxf(feat[gi * 3 + 0], 0.0f), 1.0f);
  const float colg = fminf(fmaxf(feat[gi * 3 + 1], 0.0f), 1.0f);
  const float colb = fminf(fmaxf(feat[gi * 3 + 2], 0.0f), 1.0f);
  const float base = fminf(fmaxf(opac[gi], 0.0f), 1.0f);
  const float dyn  = fminf(fmaxf(1.0f - bg[gi], 0.0f), 1.0f);
  const float aAll = base;
  const float aDyn = base * dyn;           // <= aAll
  const float aSta = base * (1.0f - dyn);  // <= aAll

  // world = first_pose @ [c,1]  (exact when first_pose == I)
  float wd[4];
  for (int i = 0; i < 4; ++i)
    wd[i] = ((fpose[i * 4 + 0] * c0 + fpose[i * 4 + 1] * c1) + fpose[i * 4 + 2] * c2) +
            fpose[i * 4 + 3] * 1.0f;

  const float cam0 = ((M0 * wd[0] + M1 * wd[1]) + M2  * wd[2]) + M3  * wd[3];
  const float cam1 = ((M4 * wd[0] + M5 * wd[1]) + M6  * wd[2]) + M7  * wd[3];
  const float cam2 = ((M8 * wd[0] + M9 * wd[1]) + M10 * wd[2]) + M11 * wd[3];
  const bool fin = (fabsf(cam0) <= 3.4028235e38f) && (fabsf(cam1) <= 3.4028235e38f) &&
                   (fabsf(cam2) <= 3.4028235e38f);
  const float z = cam2;
  const float fx = intr[v * 4 + 0], fy = intr[v * 4 + 1];
  const float ppx = intr[v * 4 + 2], ppy = intr[v * 4 + 3];

  bool kept = false;
  float u = 0.0f, vv2 = 0.0f, sig = 0.0f;
  if ((z > 0.001f) && fin) {
    u   = cam0 * fx / z + ppx;            // exact op sequence of the reference
    vv2 = cam1 * fy / z + ppy;
    float tsc = (fx + fy) * 0.5f;
    sig = tsc * fabsf(sf);
    sig = sig / fmaxf(z, 0.001f);
    sig = fminf(fmaxf(sig, 0.75f), 10.0f);
    const bool inb = (u >= -3.0f) && (u <= 450.0f) && (vv2 >= -3.0f) && (vv2 <= 226.0f);
    kept = inb && (aAll > 1e-5f);
  }

  if (kept) {
    const int x0 = (int)floorf(u);
    const int y0 = (int)floorf(vv2);
    const float rc = ceilf(sig * 1.5f);   // RADIUS_SCALE
    const int rad = rc < 1.0f ? 1 : (rc > 2.0f ? 2 : (int)rc);
    const int pk = ((x0 + 4) << 16) | ((y0 + 4) << 4) | rad;
    WqA[idx] = make_float4(z, u, vv2, sig);
    WqB[idx] = make_float4(__int_as_float(pk), colr, colg, colb);
    WqC[idx] = make_float4(aAll, aDyn, aSta, 0.0f);
    // ---- scatter binning to 8x8 tiles (bbox interval-overlap) ----
    const int x_lo = x0 - rad, x_hi = x0 + rad;
    const int y_lo = y0 - rad, y_hi = y0 + rad;
    if (x_hi >= 0 && x_lo < Ww && y_hi >= 0 && y_lo < Hh) {
      const int tx_lo = (x_lo > 0 ? x_lo : 0) >> 3;
      const int tx_hi = (x_hi < Ww - 1 ? x_hi : Ww - 1) >> 3;
      const int ty_lo = (y_lo > 0 ? y_lo : 0) >> 3;
      const int ty_hi = (y_hi < Hh - 1 ? y_hi : Hh - 1) >> 3;
      for (int ty = ty_lo; ty <= ty_hi; ++ty)
        for (int tx = tx_lo; tx <= tx_hi; ++tx) {
          const int tile = (tv * NTY + ty) * NTX + tx;
          const int slot = atomicAdd(&Wtcnt[tile], 1);
          if (slot < CAP_T) Wlist[(size_t)tile * CAP_T + slot] = n;
        }
    }
  }

  // ---- sigma_mean reduction: wave shuffle -> LDS -> ONE atomic pair per block
  float sred = kept ? sig : 0.0f;
  int   cred = kept ? 1 : 0;
  #pragma unroll
  for (int off = 32; off > 0; off >>= 1) {
    sred += __shfl_down(sred, off, 64);
    cred += __shfl_down(cred, off, 64);
  }
  __shared__ float bsum[4];
  __shared__ int   bcnt[4];
  const int wv = threadIdx.x >> 6;
  if ((threadIdx.x & 63) == 0) { bsum[wv] = sred; bcnt[wv] = cred; }
  __syncthreads();
  if (threadIdx.x == 0) {
    const float ts = ((bsum[0] + bsum[1]) + bsum[2]) + bsum[3];
    const int   tc = bcnt[0] + bcnt[1] + bcnt[2] + bcnt[3];
    if (tc > 0) {
      atomicAdd(&Wsum[tv], ts);
      atomicAdd(&Wcnt[tv], tc);
    }
  }
}

// One wave (64 threads) per 8x8 tile. Single-wave blocks: __syncthreads is
// effectively free, and the cnt<=64 sort is a pure in-register shuffle bitonic.
// Fused finalize with ZERO waits/fences and near-zero contention: each block
// does ONE packed atomicAdd (count<<16 | popcount) on its 64-tile group word;
// the RMW return value tells the group-last block the exact group total. 98
// group-lasts do one packed u64 atomicAdd on a single global word; the
// device-last block writes the two scalars. (Round-2 lesson: 12.5k serialized
// same-address atomics + vmcnt(0) waits cost ~110 µs.)
__global__ __launch_bounds__(64) void raster_k(float* __restrict__ ws,
                                               float* __restrict__ out) {
#pragma clang fp contract(off)
  __shared__ unsigned long long s_key[CAP_T];
  __shared__ float4 sA[64], sB[64], sC[64];

  const int tid = threadIdx.x;   // 0..63
  const int tv  = blockIdx.z;
  const int px  = blockIdx.x * TILE + (tid & 7);
  const int py  = blockIdx.y * TILE + (tid >> 3);
  const float fpx = (float)px, fpy = (float)py;
  const size_t base = (size_t)tv * Nn;

  const float4* WqA = (const float4*)(ws + WS_QA);
  const float4* WqB = (const float4*)(ws + WS_QB);
  const float4* WqC = (const float4*)(ws + WS_QC);
  const float* Wsum = ws + WS_SUM;
  const int*   Wcnt = (const int*)(ws + WS_CNT);
  unsigned long long* Wglb = (unsigned long long*)(ws + WS_GLB);
  int* Wgrp = (int*)(ws + WS_GRP);
  const int* Wtcnt = (const int*)(ws + WS_TCNT);
  const int* Wlist = (const int*)(ws + WS_LIST);

  const int tile = (tv * NTY + blockIdx.y) * NTX + blockIdx.x;
  const int cnt0 = Wtcnt[tile];
  const int cnt  = cnt0 < CAP_T ? cnt0 : CAP_T;
  const int* mylist = Wlist + (size_t)tile * CAP_T;

  float Aall = 0.0f, Adyn = 0.0f, Asta = 0.0f;
  float Ra = 0.0f, Ga = 0.0f, Ba = 0.0f;
  float Rd = 0.0f, Gd = 0.0f, Bd = 0.0f;
  float Rs = 0.0f, Gs = 0.0f, Bs = 0.0f;

  auto composite = [&](int m) {
    for (int j = 0; j < m; ++j) {
      const float4 qb = sB[j];                 // (pk, r, g, b) — LDS broadcast
      const int pk  = __float_as_int(qb.x);
      const int rad = pk & 15;
      const int y0  = ((pk >> 4) & 0xfff) - 4;
      const int x0  = (pk >> 16) - 4;
      if (abs(px - x0) <= rad && abs(py - y0) <= rad) {
        const float4 qa = sA[j];               // (z, u, v, sig)
        const float sg = qa.w;
        const float du = (qa.y - fpx) / sg;
        const float dv = (qa.z - fpy) / sg;
        const float gs = expf(-0.5f * (du * du + dv * dv));
        const float4 qc = sC[j];               // (aAll, aDyn, aSta, 0)
        {  // "all" branch: list membership implies aAll > 1e-5
          const float la = fminf(fmaxf(gs * qc.x, 0.0f), 0.999f);
          const float tr = fminf(fmaxf(1.0f - Aall, 0.0f), 1.0f);
          const float ct = la * tr;
          Ra += qb.y * ct; Ga += qb.z * ct; Ba += qb.w * ct;
          Aall = fminf(fmaxf(Aall + ct, 0.0f), 0.999f);
        }
        if (qc.y > 1e-5f) {
          const float la = fminf(fmaxf(gs * qc.y, 0.0f), 0.999f);
          const float tr = fminf(fmaxf(1.0f - Adyn, 0.0f), 1.0f);
          const float ct = la * tr;
          Rd += qb.y * ct; Gd += qb.z * ct; Bd += qb.w * ct;
          Adyn = fminf(fmaxf(Adyn + ct, 0.0f), 0.999f);
        }
        if (qc.z > 1e-5f) {
          const float la = fminf(fmaxf(gs * qc.z, 0.0f), 0.999f);
          const float tr = fminf(fmaxf(1.0f - Asta, 0.0f), 1.0f);
          const float ct = la * tr;
          Rs += qb.y * ct; Gs += qb.z * ct; Bs += qb.w * ct;
          Asta = fminf(fmaxf(Asta + ct, 0.0f), 0.999f);
        }
      }
    }
  };

  if (cnt <= 64) {
    // ---- in-register wave bitonic on (z_bits, n): no LDS, no barriers.
    // z>0 so float-bit order == value order; index tiebreak == stable argsort.
    unsigned long long key = ~0ULL;
    if (tid < cnt) {
      const unsigned int n = (unsigned int)mylist[tid];
      const float z = ws[WS_QA + 4 * (base + (size_t)n)];  // WqA[.].x
      key = ((unsigned long long)__float_as_uint(z) << 32) | n;
    }
    if (cnt > 1) {
      for (int k = 2; k <= 64; k <<= 1) {
        for (int j = k >> 1; j > 0; j >>= 1) {
          const unsigned long long other = shfl_xor_u64(key, j);
          const bool up = ((tid & k) == 0);
          const bool keep_min = (up == ((tid & j) == 0));
          key = keep_min ? (key < other ? key : other) : (key > other ? key : other);
        }
      }
    }
    if (tid < cnt) {  // lane tid holds rank-tid entry; stage it (3x 16B gather)
      const size_t a = base + (size_t)(int)(key & 0xffffffffULL);
      sA[tid] = WqA[a]; sB[tid] = WqB[a]; sC[tid] = WqC[a];
    }
    __syncthreads();   // single wave: near-free, orders LDS writes->reads
    composite(cnt);
  } else {
    // ---- LDS bitonic over P = next pow2 (<= 256), 64 threads striding ----
    for (int i = tid; i < cnt; i += 64) {
      const unsigned int n = (unsigned int)mylist[i];
      const float z = ws[WS_QA + 4 * (base + (size_t)n)];
      s_key[i] = ((unsigned long long)__float_as_uint(z) << 32) | n;
    }
    int P = 1;
    while (P < cnt) P <<= 1;
    for (int i = cnt + tid; i < P; i += 64) s_key[i] = ~0ULL;
    __syncthreads();
    for (int k = 2; k <= P; k <<= 1) {
      for (int j = k >> 1; j > 0; j >>= 1) {
        for (int i = tid; i < P; i += 64) {
          const int ixj = i ^ j;
          if (ixj > i) {
            const unsigned long long a = s_key[i], b2 = s_key[ixj];
            const bool up = ((i & k) == 0);
            if ((a > b2) == up) { s_key[i] = b2; s_key[ixj] = a; }
          }
        }
        __syncthreads();
      }
    }
    for (int cb = 0; cb < cnt; cb += 64) {
      const int m = min(64, cnt - cb);
      if (tid < m) {
        const size_t a = base + (size_t)(int)(s_key[cb + tid] & 0xffffffffULL);
        sA[tid] = WqA[a]; sB[tid] = WqB[a]; sC[tid] = WqC[a];
      }
      __syncthreads();
      composite(m);
      __syncthreads();
    }
  }

  // ---- write outputs ----
  const size_t pix = (size_t)py * Ww + px;
  const size_t hw  = (size_t)HW;
  const size_t m3  = (size_t)tv * 3;
  out[OFF_RGB_STA + (m3 + 0) * hw + pix] = fminf(fmaxf(Rs, 0.0f), 1.0f);
  out[OFF_RGB_STA + (m3 + 1) * hw + pix] = fminf(fmaxf(Gs, 0.0f), 1.0f);
  out[OFF_RGB_STA + (m3 + 2) * hw + pix] = fminf(fmaxf(Bs, 0.0f), 1.0f);
  out[OFF_RGB_DYN + (m3 + 0) * hw + pix] = fminf(fmaxf(Rd, 0.0f), 1.0f);
  out[OFF_RGB_DYN + (m3 + 1) * hw + pix] = fminf(fmaxf(Gd, 0.0f), 1.0f);
  out[OFF_RGB_DYN + (m3 + 2) * hw + pix] = fminf(fmaxf(Bd, 0.0f), 1.0f);
  out[OFF_RGB_ALL + (m3 + 0) * hw + pix] = fminf(fmaxf(Ra, 0.0f), 1.0f);
  out[OFF_RGB_ALL + (m3 + 1) * hw + pix] = fminf(fmaxf(Ga, 0.0f), 1.0f);
  out[OFF_RGB_ALL + (m3 + 2) * hw + pix] = fminf(fmaxf(Ba, 0.0f), 1.0f);
  out[OFF_AL_STA + (size_t)tv * hw + pix] = fminf(fmaxf(Asta, 0.0f), 1.0f);
  out[OFF_AL_DYN + (size_t)tv * hw + pix] = fminf(fmaxf(Adyn, 0.0f), 1.0f);
  out[OFF_AL_ALL + (size_t)tv * hw + pix] = fminf(fmaxf(Aall, 0.0f), 1.0f);

  // ---- fused finalize: one packed atomic per block, no waits, no fences ----
  const unsigned long long bal = __ballot(Aall > 1e-6f);
  if (tid == 0) {
    const int pc = (int)__popcll(bal);                    // <= 64
    const int grp = tile >> 6;                            // 98 exact groups
    const int gold = atomicAdd(&Wgrp[grp], (1 << 16) | pc);
    if ((gold >> 16) == 63) {                             // group-last block
      const unsigned int gtot = (unsigned int)((gold & 0xffff) + pc);
      const unsigned long long old =
          atomicAdd(Wglb, (1ULL << 32) | (unsigned long long)gtot);
      if ((old >> 32) == (unsigned long long)(NGRP - 1)) {  // device-last
        const unsigned int grand = (unsigned int)(old & 0xffffffffULL) + gtot;
        float sm = 0.0f;
        for (int i = 0; i < TV; ++i) {
          const int c = Wcnt[i];   // written by prep_k: kernel-boundary ordered
          sm += (c > 0) ? (Wsum[i] / (float)(c > 1 ? c : 1)) : 0.0f;
        }
        out[OFF_SM]    = sm / (float)TV;
        out[OFF_TOUCH] = (float)grand / (float)(HW * TV);
      }
    }
  }
}

extern "C" void kernel_launch(void* const* d_in, const int* in_sizes, int n_in,
                              void* d_out, int out_size, void* d_ws, size_t ws_size,
                              hipStream_t stream) {
  const float* center = (const float*)d_in[0];
  const float* scale  = (const float*)d_in[1];
  const float* feat   = (const float*)d_in[2];
  const float* opac   = (const float*)d_in[3];
  const float* bg     = (const float*)d_in[4];
  const float* sem    = (const float*)d_in[5];
  const float* intr   = (const float*)d_in[6];
  const float* c2w    = (const float*)d_in[7];
  const float* fpose  = (const float*)d_in[8];
  float* out = (float*)d_out;
  float* ws  = (float*)d_ws;

  const int copy_blocks = (int)((RGB_SZ / 4 + 255) / 256) + 1;  // last block zeroes
  hipLaunchKernelGGL(init_k, dim3(copy_blocks), dim3(256), 0, stream,
                     (const float4*)sem, (float4*)(out + OFF_SEM), ws);
  hipLaunchKernelGGL(prep_k, dim3(TOT / 256), dim3(256), 0, stream,
                     center, scale, feat, opac, bg, intr, fpose, c2w, ws);
  hipLaunchKernelGGL(raster_k, dim3(NTX, NTY, TV), dim3(64), 0, stream, ws, out);
}

// Round 4
// 122.391 us; speedup vs baseline: 2.9000x; 1.0252x over previous
//
#include <hip/hip_runtime.h>
#include <cmath>

namespace {
constexpr int Hh = 224, Ww = 448;
constexpr int Tt = 2, Vv = 2, GH = 56, GW = 112;
constexpr int Nn = Vv * GH * GW;       // 12544 gaussians per (t) set
constexpr int TV = Tt * Vv;            // 4 render views
constexpr int TOT = TV * Nn;           // 50176 (view,gaussian) pairs
constexpr int HW = Hh * Ww;            // 100352
constexpr int TILE = 8;                // 8x8 tiles, one wave per tile
constexpr int NTX = Ww / TILE;         // 56
constexpr int NTY = Hh / TILE;         // 28
constexpr int NTILES = TV * NTX * NTY; // 6272
constexpr int CAP_T = 256;             // per-tile list capacity (expected peak ~80)
constexpr int NGRP = NTILES / 64;      // 98 exact groups of 64 tiles

constexpr size_t RGB_SZ = (size_t)TV * 3 * HW;   // 1204224
constexpr size_t AL_SZ  = (size_t)TV * HW;       // 401408
constexpr size_t OFF_RGB_STA = 0;
constexpr size_t OFF_RGB_DYN = RGB_SZ;
constexpr size_t OFF_RGB_ALL = 2 * RGB_SZ;
constexpr size_t OFF_AL_STA  = 3 * RGB_SZ;
constexpr size_t OFF_AL_DYN  = 3 * RGB_SZ + AL_SZ;
constexpr size_t OFF_AL_ALL  = 3 * RGB_SZ + 2 * AL_SZ;
constexpr size_t OFF_SEM     = 3 * RGB_SZ + 3 * AL_SZ;
constexpr size_t OFF_SM      = OFF_SEM + RGB_SZ;
constexpr size_t OFF_TOUCH   = OFF_SM + 1;

// ---- ws layout (floats) ----
// Packed per-(tv,n) gaussian records, 3 float4 arrays:
//   QA = (z, u, v, sig) | QB = (pk_bits, r, g, b) | QC = (aAll, aDyn, aSta, 0)
// then: 4 f sum_sigma | 4 i cnt | 2 w u64 global (count<<32 | touch) |
//       NGRP i group (count<<16 | touch) | NTILES i tile-counters |
//       NTILES*CAP_T i tile lists
constexpr size_t WS_QA   = 0;
constexpr size_t WS_QB   = (size_t)4 * TOT;
constexpr size_t WS_QC   = (size_t)8 * TOT;
constexpr size_t WS_SUM  = (size_t)12 * TOT;   // word offset; *4 bytes is 8B-aligned
constexpr size_t WS_CNT  = WS_SUM + 4;
constexpr size_t WS_GLB  = WS_CNT + 4;         // u64, 8B aligned (offset even)
constexpr size_t WS_GRP  = WS_GLB + 2;
constexpr size_t WS_TCNT = WS_GRP + NGRP;
constexpr size_t WS_LIST = WS_TCNT + NTILES;
constexpr int    N_ZERO  = 10 + NGRP + NTILES;  // Wsum+Wcnt+glb+grp+Wtcnt = 6380
} // namespace

__device__ inline unsigned long long shfl_xor_u64(unsigned long long x, int m) {
  unsigned int lo = (unsigned int)x, hi = (unsigned int)(x >> 32);
  lo = __shfl_xor(lo, m, 64);
  hi = __shfl_xor(hi, m, 64);
  return ((unsigned long long)hi << 32) | lo;
}

// Tiny zero-only kernel (25 blocks): the 4.8 MB sem copy moved into prep_k
// where it overlaps the fp64 matrix work. NO fences anywhere in the pipeline
// (round-1 lesson: per-block agent-scope cache maintenance ~= 5x regression).
__global__ __launch_bounds__(256) void zero_k(float* __restrict__ ws) {
  const int i = blockIdx.x * 256 + threadIdx.x;
  if (i < N_ZERO) ((int*)(ws + WS_SUM))[i] = 0;
}

__global__ __launch_bounds__(256) void prep_k(
    const float* __restrict__ center, const float* __restrict__ scale,
    const float* __restrict__ feat, const float* __restrict__ opac,
    const float* __restrict__ bg, const float* __restrict__ intr,
    const float* __restrict__ fpose, const float* __restrict__ c2w,
    float* __restrict__ ws, const float4* __restrict__ sem,
    float4* __restrict__ semdst) {
#pragma clang fp contract(off)
  const int idx = blockIdx.x * 256 + threadIdx.x;

  // ---- fused sem copy: RGB_SZ/4 float4s = exactly 6*TOT; coalesced, and the
  // loads overlap the register-resident fp64 inverse below.
  #pragma unroll
  for (int k = 0; k < 6; ++k) semdst[idx + k * TOT] = sem[idx + k * TOT];

  // Nn = 12544 = 49*256, so tv is uniform across the block.
  const int n  = idx % Nn;
  const int tv = idx / Nn;
  const int v  = tv % Vv;
  const int t  = tv / Vv;
  const size_t gi = (size_t)t * Nn + n;   // gaussian params depend on (t,n) only

  float4* WqA = (float4*)(ws + WS_QA);
  float4* WqB = (float4*)(ws + WS_QB);
  float4* WqC = (float4*)(ws + WS_QC);
  float* Wsum = ws + WS_SUM;
  int*   Wcnt = (int*)(ws + WS_CNT);
  int*   Wtcnt = (int*)(ws + WS_TCNT);
  int*   Wlist = (int*)(ws + WS_LIST);

  // ---- w2c = inv(c2w[tv]) via fp64 adjugate (unrolled, register-resident).
  // Rotation is exactly identity here, so the result is exactly [I | -t] —
  // matches the fp32 reference inverse bitwise.
  double m00, m01, m02, m03, m10, m11, m12, m13,
         m20, m21, m22, m23, m30, m31, m32, m33;
  {
    const float* C = c2w + (size_t)tv * 16;
    m00 = C[0];  m01 = C[1];  m02 = C[2];  m03 = C[3];
    m10 = C[4];  m11 = C[5];  m12 = C[6];  m13 = C[7];
    m20 = C[8];  m21 = C[9];  m22 = C[10]; m23 = C[11];
    m30 = C[12]; m31 = C[13]; m32 = C[14]; m33 = C[15];
  }
  const double s0d = m00 * m11 - m10 * m01;
  const double s1d = m00 * m12 - m10 * m02;
  const double s2d = m00 * m13 - m10 * m03;
  const double s3d = m01 * m12 - m11 * m02;
  const double s4d = m01 * m13 - m11 * m03;
  const double s5d = m02 * m13 - m12 * m03;
  const double c5d = m22 * m33 - m32 * m23;
  const double c4d = m21 * m33 - m31 * m23;
  const double c3d = m21 * m32 - m31 * m22;
  const double c2d = m20 * m33 - m30 * m23;
  const double c1d = m20 * m32 - m30 * m22;
  const double c0d = m20 * m31 - m30 * m21;
  const double invdet =
      1.0 / (s0d * c5d - s1d * c4d + s2d * c3d + s3d * c2d - s4d * c1d + s5d * c0d);
  const float M0  = (float)(( m11 * c5d - m12 * c4d + m13 * c3d) * invdet);
  const float M1  = (float)((-m01 * c5d + m02 * c4d - m03 * c3d) * invdet);
  const float M2  = (float)(( m31 * s5d - m32 * s4d + m33 * s3d) * invdet);
  const float M3  = (float)((-m21 * s5d + m22 * s4d - m23 * s3d) * invdet);
  const float M4  = (float)((-m10 * c5d + m12 * c2d - m13 * c1d) * invdet);
  const float M5  = (float)(( m00 * c5d - m02 * c2d + m03 * c1d) * invdet);
  const float M6  = (float)((-m30 * s5d + m32 * s2d - m33 * s1d) * invdet);
  const float M7  = (float)(( m20 * s5d - m22 * s2d + m23 * s1d) * invdet);
  const float M8  = (float)(( m10 * c4d - m11 * c2d + m13 * c0d) * invdet);
  const float M9  = (float)((-m00 * c4d + m01 * c2d - m03 * c0d) * invdet);
  const float M10 = (float)(( m30 * s4d - m31 * s2d + m33 * s0d) * invdet);
  const float M11 = (float)((-m20 * s4d + m21 * s2d - m23 * s0d) * invdet);

  const float c0 = center[gi * 3 + 0], c1 = center[gi * 3 + 1], c2 = center[gi * 3 + 2];
  const float s0 = scale[gi * 3 + 0], s1 = scale[gi * 3 + 1], s2 = scale[gi * 3 + 2];
  const float sf = ((s0 + s1) + s2) / 3.0f;                 // jnp.mean(axis=-1)
  const float colr = fminf(fmaxf(feat[gi * 3 + 0], 0.0f), 1.0f);
  const float colg = fminf(fmaxf(feat[gi * 3 + 1], 0.0f), 1.0f);
  const float colb = fminf(fmaxf(feat[gi * 3 + 2], 0.0f), 1.0f);
  const float base = fminf(fmaxf(opac[gi], 0.0f), 1.0f);
  const float dyn  = fminf(fmaxf(1.0f - bg[gi], 0.0f), 1.0f);
  const float aAll = base;
  const float aDyn = base * dyn;           // <= aAll
  const float aSta = base * (1.0f - dyn);  // <= aAll

  // world = first_pose @ [c,1]  (exact when first_pose == I)
  float wd[4];
  for (int i = 0; i < 4; ++i)
    wd[i] = ((fpose[i * 4 + 0] * c0 + fpose[i * 4 + 1] * c1) + fpose[i * 4 + 2] * c2) +
            fpose[i * 4 + 3] * 1.0f;

  const float cam0 = ((M0 * wd[0] + M1 * wd[1]) + M2  * wd[2]) + M3  * wd[3];
  const float cam1 = ((M4 * wd[0] + M5 * wd[1]) + M6  * wd[2]) + M7  * wd[3];
  const float cam2 = ((M8 * wd[0] + M9 * wd[1]) + M10 * wd[2]) + M11 * wd[3];
  const bool fin = (fabsf(cam0) <= 3.4028235e38f) && (fabsf(cam1) <= 3.4028235e38f) &&
                   (fabsf(cam2) <= 3.4028235e38f);
  const float z = cam2;
  const float fx = intr[v * 4 + 0], fy = intr[v * 4 + 1];
  const float ppx = intr[v * 4 + 2], ppy = intr[v * 4 + 3];

  bool kept = false;
  float u = 0.0f, vv2 = 0.0f, sig = 0.0f;
  if ((z > 0.001f) && fin) {
    u   = cam0 * fx / z + ppx;            // exact op sequence of the reference
    vv2 = cam1 * fy / z + ppy;
    float tsc = (fx + fy) * 0.5f;
    sig = tsc * fabsf(sf);
    sig = sig / fmaxf(z, 0.001f);
    sig = fminf(fmaxf(sig, 0.75f), 10.0f);
    const bool inb = (u >= -3.0f) && (u <= 450.0f) && (vv2 >= -3.0f) && (vv2 <= 226.0f);
    kept = inb && (aAll > 1e-5f);
  }

  if (kept) {
    const int x0 = (int)floorf(u);
    const int y0 = (int)floorf(vv2);
    const float rc = ceilf(sig * 1.5f);   // RADIUS_SCALE
    const int rad = rc < 1.0f ? 1 : (rc > 2.0f ? 2 : (int)rc);
    const int pk = ((x0 + 4) << 16) | ((y0 + 4) << 4) | rad;
    WqA[idx] = make_float4(z, u, vv2, sig);
    WqB[idx] = make_float4(__int_as_float(pk), colr, colg, colb);
    WqC[idx] = make_float4(aAll, aDyn, aSta, 0.0f);
    // ---- scatter binning to 8x8 tiles (bbox interval-overlap) ----
    const int x_lo = x0 - rad, x_hi = x0 + rad;
    const int y_lo = y0 - rad, y_hi = y0 + rad;
    if (x_hi >= 0 && x_lo < Ww && y_hi >= 0 && y_lo < Hh) {
      const int tx_lo = (x_lo > 0 ? x_lo : 0) >> 3;
      const int tx_hi = (x_hi < Ww - 1 ? x_hi : Ww - 1) >> 3;
      const int ty_lo = (y_lo > 0 ? y_lo : 0) >> 3;
      const int ty_hi = (y_hi < Hh - 1 ? y_hi : Hh - 1) >> 3;
      for (int ty = ty_lo; ty <= ty_hi; ++ty)
        for (int tx = tx_lo; tx <= tx_hi; ++tx) {
          const int tile = (tv * NTY + ty) * NTX + tx;
          const int slot = atomicAdd(&Wtcnt[tile], 1);
          if (slot < CAP_T) Wlist[(size_t)tile * CAP_T + slot] = n;
        }
    }
  }

  // ---- sigma_mean reduction: wave shuffle -> LDS -> ONE atomic pair per block
  float sred = kept ? sig : 0.0f;
  int   cred = kept ? 1 : 0;
  #pragma unroll
  for (int off = 32; off > 0; off >>= 1) {
    sred += __shfl_down(sred, off, 64);
    cred += __shfl_down(cred, off, 64);
  }
  __shared__ float bsum[4];
  __shared__ int   bcnt[4];
  const int wv = threadIdx.x >> 6;
  if ((threadIdx.x & 63) == 0) { bsum[wv] = sred; bcnt[wv] = cred; }
  __syncthreads();
  if (threadIdx.x == 0) {
    const float ts = ((bsum[0] + bsum[1]) + bsum[2]) + bsum[3];
    const int   tc = bcnt[0] + bcnt[1] + bcnt[2] + bcnt[3];
    if (tc > 0) {
      atomicAdd(&Wsum[tv], ts);
      atomicAdd(&Wcnt[tv], tc);
    }
  }
}

// One wave (64 threads) per 8x8 tile. Single-wave blocks: __syncthreads is
// effectively free, and the cnt<=64 sort is a pure in-register shuffle bitonic.
// Fused finalize with ZERO waits/fences and near-zero contention: each block
// does ONE packed atomicAdd (count<<16 | popcount) on its 64-tile group word;
// the RMW return value tells the group-last block the exact group total. 98
// group-lasts do one packed u64 atomicAdd on a single global word; the
// device-last block writes the two scalars. (Round-2 lesson: 12.5k serialized
// same-address atomics + vmcnt(0) waits cost ~110 µs.)
__global__ __launch_bounds__(64) void raster_k(float* __restrict__ ws,
                                               float* __restrict__ out) {
#pragma clang fp contract(off)
  __shared__ unsigned long long s_key[CAP_T];
  __shared__ float4 sA[64], sB[64], sC[64];

  const int tid = threadIdx.x;   // 0..63
  const int tv  = blockIdx.z;
  const int px  = blockIdx.x * TILE + (tid & 7);
  const int py  = blockIdx.y * TILE + (tid >> 3);
  const float fpx = (float)px, fpy = (float)py;
  const size_t base = (size_t)tv * Nn;

  const float4* WqA = (const float4*)(ws + WS_QA);
  const float4* WqB = (const float4*)(ws + WS_QB);
  const float4* WqC = (const float4*)(ws + WS_QC);
  const float* Wsum = ws + WS_SUM;
  const int*   Wcnt = (const int*)(ws + WS_CNT);
  unsigned long long* Wglb = (unsigned long long*)(ws + WS_GLB);
  int* Wgrp = (int*)(ws + WS_GRP);
  const int* Wtcnt = (const int*)(ws + WS_TCNT);
  const int* Wlist = (const int*)(ws + WS_LIST);

  const int tile = (tv * NTY + blockIdx.y) * NTX + blockIdx.x;
  const int* mylist = Wlist + (size_t)tile * CAP_T;

  // ---- latency: issue cnt, list[tid], and a clamped z gather as one
  // independent chain instead of three serial HBM round trips.
  const unsigned int n_pre = (unsigned int)mylist[tid];
  const unsigned int n_safe = n_pre < (unsigned int)Nn ? n_pre : 0;  // poison-safe
  const float z_pre = ws[WS_QA + 4 * (base + (size_t)n_safe)];       // WqA[.].x
  const int cnt0 = Wtcnt[tile];
  const int cnt  = cnt0 < CAP_T ? cnt0 : CAP_T;

  float Aall = 0.0f, Adyn = 0.0f, Asta = 0.0f;
  float Ra = 0.0f, Ga = 0.0f, Ba = 0.0f;
  float Rd = 0.0f, Gd = 0.0f, Bd = 0.0f;
  float Rs = 0.0f, Gs = 0.0f, Bs = 0.0f;

  auto composite = [&](int m) {
    for (int j = 0; j < m; ++j) {
      const float4 qb = sB[j];                 // (pk, r, g, b) — LDS broadcast
      const int pk  = __float_as_int(qb.x);
      const int rad = pk & 15;
      const int y0  = ((pk >> 4) & 0xfff) - 4;
      const int x0  = (pk >> 16) - 4;
      if (abs(px - x0) <= rad && abs(py - y0) <= rad) {
        const float4 qa = sA[j];               // (z, u, v, sig)
        const float sg = qa.w;
        const float du = (qa.y - fpx) / sg;
        const float dv = (qa.z - fpy) / sg;
        const float gs = expf(-0.5f * (du * du + dv * dv));
        const float4 qc = sC[j];               // (aAll, aDyn, aSta, 0)
        {  // "all" branch: list membership implies aAll > 1e-5
          const float la = fminf(fmaxf(gs * qc.x, 0.0f), 0.999f);
          const float tr = fminf(fmaxf(1.0f - Aall, 0.0f), 1.0f);
          const float ct = la * tr;
          Ra += qb.y * ct; Ga += qb.z * ct; Ba += qb.w * ct;
          Aall = fminf(fmaxf(Aall + ct, 0.0f), 0.999f);
        }
        if (qc.y > 1e-5f) {
          const float la = fminf(fmaxf(gs * qc.y, 0.0f), 0.999f);
          const float tr = fminf(fmaxf(1.0f - Adyn, 0.0f), 1.0f);
          const float ct = la * tr;
          Rd += qb.y * ct; Gd += qb.z * ct; Bd += qb.w * ct;
          Adyn = fminf(fmaxf(Adyn + ct, 0.0f), 0.999f);
        }
        if (qc.z > 1e-5f) {
          const float la = fminf(fmaxf(gs * qc.z, 0.0f), 0.999f);
          const float tr = fminf(fmaxf(1.0f - Asta, 0.0f), 1.0f);
          const float ct = la * tr;
          Rs += qb.y * ct; Gs += qb.z * ct; Bs += qb.w * ct;
          Asta = fminf(fmaxf(Asta + ct, 0.0f), 0.999f);
        }
      }
    }
  };

  if (cnt <= 64) {
    // ---- in-register wave bitonic on (z_bits, n): no LDS, no barriers.
    // z>0 so float-bit order == value order; index tiebreak == stable argsort.
    unsigned long long key = ~0ULL;
    if (tid < cnt)
      key = ((unsigned long long)__float_as_uint(z_pre) << 32) | n_pre;
    if (cnt > 1) {
      for (int k = 2; k <= 64; k <<= 1) {
        for (int j = k >> 1; j > 0; j >>= 1) {
          const unsigned long long other = shfl_xor_u64(key, j);
          const bool up = ((tid & k) == 0);
          const bool keep_min = (up == ((tid & j) == 0));
          key = keep_min ? (key < other ? key : other) : (key > other ? key : other);
        }
      }
    }
    if (tid < cnt) {  // lane tid holds rank-tid entry; stage it (3x 16B gather)
      const size_t a = base + (size_t)(int)(key & 0xffffffffULL);
      sA[tid] = WqA[a]; sB[tid] = WqB[a]; sC[tid] = WqC[a];
    }
    __syncthreads();   // single wave: near-free, orders LDS writes->reads
    composite(cnt);
  } else {
    // ---- LDS bitonic over P = next pow2 (<= 256), 64 threads striding ----
    for (int i = tid; i < cnt; i += 64) {
      const unsigned int n = (unsigned int)mylist[i];
      const float z = ws[WS_QA + 4 * (base + (size_t)n)];
      s_key[i] = ((unsigned long long)__float_as_uint(z) << 32) | n;
    }
    int P = 1;
    while (P < cnt) P <<= 1;
    for (int i = cnt + tid; i < P; i += 64) s_key[i] = ~0ULL;
    __syncthreads();
    for (int k = 2; k <= P; k <<= 1) {
      for (int j = k >> 1; j > 0; j >>= 1) {
        for (int i = tid; i < P; i += 64) {
          const int ixj = i ^ j;
          if (ixj > i) {
            const unsigned long long a = s_key[i], b2 = s_key[ixj];
            const bool up = ((i & k) == 0);
            if ((a > b2) == up) { s_key[i] = b2; s_key[ixj] = a; }
          }
        }
        __syncthreads();
      }
    }
    for (int cb = 0; cb < cnt; cb += 64) {
      const int m = min(64, cnt - cb);
      if (tid < m) {
        const size_t a = base + (size_t)(int)(s_key[cb + tid] & 0xffffffffULL);
        sA[tid] = WqA[a]; sB[tid] = WqB[a]; sC[tid] = WqC[a];
      }
      __syncthreads();
      composite(m);
      __syncthreads();
    }
  }

  // ---- write outputs ----
  const size_t pix = (size_t)py * Ww + px;
  const size_t hw  = (size_t)HW;
  const size_t m3  = (size_t)tv * 3;
  out[OFF_RGB_STA + (m3 + 0) * hw + pix] = fminf(fmaxf(Rs, 0.0f), 1.0f);
  out[OFF_RGB_STA + (m3 + 1) * hw + pix] = fminf(fmaxf(Gs, 0.0f), 1.0f);
  out[OFF_RGB_STA + (m3 + 2) * hw + pix] = fminf(fmaxf(Bs, 0.0f), 1.0f);
  out[OFF_RGB_DYN + (m3 + 0) * hw + pix] = fminf(fmaxf(Rd, 0.0f), 1.0f);
  out[OFF_RGB_DYN + (m3 + 1) * hw + pix] = fminf(fmaxf(Gd, 0.0f), 1.0f);
  out[OFF_RGB_DYN + (m3 + 2) * hw + pix] = fminf(fmaxf(Bd, 0.0f), 1.0f);
  out[OFF_RGB_ALL + (m3 + 0) * hw + pix] = fminf(fmaxf(Ra, 0.0f), 1.0f);
  out[OFF_RGB_ALL + (m3 + 1) * hw + pix] = fminf(fmaxf(Ga, 0.0f), 1.0f);
  out[OFF_RGB_ALL + (m3 + 2) * hw + pix] = fminf(fmaxf(Ba, 0.0f), 1.0f);
  out[OFF_AL_STA + (size_t)tv * hw + pix] = fminf(fmaxf(Asta, 0.0f), 1.0f);
  out[OFF_AL_DYN + (size_t)tv * hw + pix] = fminf(fmaxf(Adyn, 0.0f), 1.0f);
  out[OFF_AL_ALL + (size_t)tv * hw + pix] = fminf(fmaxf(Aall, 0.0f), 1.0f);

  // ---- fused finalize: one packed atomic per block, no waits, no fences ----
  const unsigned long long bal = __ballot(Aall > 1e-6f);
  if (tid == 0) {
    const int pc = (int)__popcll(bal);                    // <= 64
    const int grp = tile >> 6;                            // 98 exact groups
    const int gold = atomicAdd(&Wgrp[grp], (1 << 16) | pc);
    if ((gold >> 16) == 63) {                             // group-last block
      const unsigned int gtot = (unsigned int)((gold & 0xffff) + pc);
      const unsigned long long old =
          atomicAdd(Wglb, (1ULL << 32) | (unsigned long long)gtot);
      if ((old >> 32) == (unsigned long long)(NGRP - 1)) {  // device-last
        const unsigned int grand = (unsigned int)(old & 0xffffffffULL) + gtot;
        float sm = 0.0f;
        for (int i = 0; i < TV; ++i) {
          const int c = Wcnt[i];   // written by prep_k: kernel-boundary ordered
          sm += (c > 0) ? (Wsum[i] / (float)(c > 1 ? c : 1)) : 0.0f;
        }
        out[OFF_SM]    = sm / (float)TV;
        out[OFF_TOUCH] = (float)grand / (float)(HW * TV);
      }
    }
  }
}

extern "C" void kernel_launch(void* const* d_in, const int* in_sizes, int n_in,
                              void* d_out, int out_size, void* d_ws, size_t ws_size,
                              hipStream_t stream) {
  const float* center = (const float*)d_in[0];
  const float* scale  = (const float*)d_in[1];
  const float* feat   = (const float*)d_in[2];
  const float* opac   = (const float*)d_in[3];
  const float* bg     = (const float*)d_in[4];
  const float* sem    = (const float*)d_in[5];
  const float* intr   = (const float*)d_in[6];
  const float* c2w    = (const float*)d_in[7];
  const float* fpose  = (const float*)d_in[8];
  float* out = (float*)d_out;
  float* ws  = (float*)d_ws;

  hipLaunchKernelGGL(zero_k, dim3((N_ZERO + 255) / 256), dim3(256), 0, stream, ws);
  hipLaunchKernelGGL(prep_k, dim3(TOT / 256), dim3(256), 0, stream,
                     center, scale, feat, opac, bg, intr, fpose, c2w, ws,
                     (const float4*)sem, (float4*)(out + OFF_SEM));
  hipLaunchKernelGGL(raster_k, dim3(NTX, NTY, TV), dim3(64), 0, stream, ws, out);
}